// Round 9
// baseline (92.936 us; speedup 1.0000x reference)
//
#include <hip/hip_runtime.h>
#include <hip/hip_bf16.h>

typedef __bf16 bf16;
typedef __bf16 bf16x4 __attribute__((ext_vector_type(4)));
typedef __bf16 bf16x8 __attribute__((ext_vector_type(8)));
typedef float f32x4 __attribute__((ext_vector_type(4)));

// async global->LDS, 16B per lane. LDS dest must be wave-uniform (HW adds lane*16).
__device__ __forceinline__ void gload16(const void* g, void* l) {
  __builtin_amdgcn_global_load_lds(
      (const __attribute__((address_space(1))) unsigned int*)g,
      (__attribute__((address_space(3))) unsigned int*)l, 16, 0, 0);
}

// Layouts (bf16, BK=64 chunks, 128B rows, swizzle: elem col ^= (row&7)<<3):
//  Pq/Pk: [bh][kb16][row c(256)][64]   (k-dim = l)  row-XOR uses c&7
//  Vt:    [bh][kb4][row l(1024)][64]   (k-dim = c)  row-XOR uses l&7
//  Pattn: [bh][kb4][row c(256)][64]    (k-dim = d)  row-XOR uses c&7

// ---------------- Kernel A: k/q/v projections in one launch (x<256:k, <512:q, else v)
__global__ __launch_bounds__(256) void proj_kqv(
    const float* __restrict__ kin, const float* __restrict__ qin,
    const float* __restrict__ vin,
    const float* __restrict__ wk, const float* __restrict__ bk,
    const float* __restrict__ wq, const float* __restrict__ bq,
    const float* __restrict__ wv, const float* __restrict__ bv,
    bf16* __restrict__ Pk, bf16* __restrict__ Pq, bf16* __restrict__ Vt) {
  int b = blockIdx.y;
  int x = blockIdx.x;
  int t = threadIdx.x;
  __shared__ float ch[4288];   // v-path only: 32*2*67
  if (x < 512) {
    // ---- k or q projection: NO LDS. Each thread reads its 2x64B rows from
    // global directly (8x j-shared -> L1 broadcast). No barrier, no conflicts.
    int g = x & 255;
    const float* in   = (x < 256) ? kin : qin;
    const float* w    = (x < 256) ? wk : wq;
    const float* bias = (x < 256) ? bk : bq;
    bf16* out         = (x < 256) ? Pk : Pq;
    const float* chg = in + ((size_t)b*256 + g)*4096;
    int j = t >> 5, i = t & 31;
    float4 wvv = reinterpret_cast<const float4*>(w)[g*8 + j];
    float bj = bias[g*8 + j];
    int h = g >> 5;
    int c = (g & 31)*8 + j;
    int bh = b*8 + h;
#pragma unroll
    for (int p = 0; p < 4; p++) {
      int l0 = p*256 + i*8;
      int m = l0 >> 5, kb = l0 >> 6, kp0 = l0 & 63, n0 = l0 & 31;
      float rr0[16], rr1[16];
      const float4* R0 = reinterpret_cast<const float4*>(chg + (2*m)*64 + 2*n0);
      const float4* R1 = reinterpret_cast<const float4*>(chg + (2*m+1)*64 + 2*n0);
#pragma unroll
      for (int u = 0; u < 4; u++) {
        *reinterpret_cast<float4*>(rr0 + u*4) = R0[u];
        *reinterpret_cast<float4*>(rr1 + u*4) = R1[u];
      }
      bf16x8 o;
#pragma unroll
      for (int u = 0; u < 8; u++)
        o[u] = (bf16)(bj + wvv.x*rr0[2*u] + wvv.y*rr0[2*u+1] + wvv.z*rr1[2*u] + wvv.w*rr1[2*u+1]);
      size_t off = (((size_t)bh*16 + kb)*256 + c)*64 + (kp0 ^ (j << 3));
      *reinterpret_cast<bf16x8*>(out + off) = o;
    }
  } else {
    // ---- v projection into swizzled chunk-transposed Vt (LDS pad 67: 2-way max)
    int r = x - 512;
    int m = r & 31, h = r >> 5;
    {
      int seg = t >> 2, part = t & 3;
      int gl = seg >> 1, ky = seg & 1;
      const float* src = vin + (((size_t)b*256 + h*32 + gl)*64 + (2*m + ky))*64;
      float* drow = ch + (gl*2 + ky)*67;
#pragma unroll
      for (int i = 0; i < 4; i++) {
        float4 v = reinterpret_cast<const float4*>(src)[part + i*4];
        int x0 = (part + i*4)*4;
        drow[x0]=v.x; drow[x0+1]=v.y; drow[x0+2]=v.z; drow[x0+3]=v.w;
      }
    }
    int cgrp = t & 31, lgr = t >> 5;
    int c0 = cgrp*8;
    float4 wv8[8]; float bb8[8];
#pragma unroll
    for (int u = 0; u < 8; u++) {
      wv8[u] = reinterpret_cast<const float4*>(wv)[h*256 + c0 + u];
      bb8[u] = bv[h*256 + c0 + u];
    }
    __syncthreads();
    const float* r0 = ch + (cgrp*2 + 0)*67;
    const float* r1 = ch + (cgrp*2 + 1)*67;
    int bh = b*8 + h;
    bf16* base = Vt + ((size_t)bh*4 + (c0 >> 6))*1024*64;
    int colx = (c0 & 63) ^ (lgr << 3);
#pragma unroll
    for (int p = 0; p < 4; p++) {
      int n = p*8 + lgr;
      int l = m*32 + n;
      float c00 = r0[2*n], c01 = r0[2*n+1], c10 = r1[2*n], c11 = r1[2*n+1];
      bf16x8 o;
#pragma unroll
      for (int u = 0; u < 8; u++)
        o[u] = (bf16)(bb8[u] + wv8[u].x*c00 + wv8[u].y*c01 + wv8[u].z*c10 + wv8[u].w*c11);
      *reinterpret_cast<bf16x8*>(base + (size_t)l*64 + colx) = o;
    }
  }
}

// ---------------- Kernel B: S = Q K^T + softmax -> Pattn.  BM=64, 256 blocks,
// 4 waves; wave tile 64c x 64d (4x4 frags, 32 MFMA/chunk).  T3/T4 2-phase
// counted-vmcnt pipeline: K+Q double-buffered LDS via gload16, vmcnt(10) never 0.
__global__ __launch_bounds__(256, 2) void attn_qk(
    const bf16* __restrict__ Pq, const bf16* __restrict__ Pk,
    bf16* __restrict__ Pattn) {
  int raw = blockIdx.x;
  int idx = raw >> 3;
  int bh = (raw & 7)*8 + (idx >> 2);   // 4 c-strips of one bh share an XCD
  int cs = idx & 3;
  int t = threadIdx.x, wave = t >> 6, lane = t & 63, lg = lane >> 4, lr = lane & 15;
  __shared__ __attribute__((aligned(16))) char smem[81920];
  bf16* Kb0 = reinterpret_cast<bf16*>(smem);            // 32 KB
  bf16* Kb1 = reinterpret_cast<bf16*>(smem + 32768);    // 32 KB
  bf16* Qb0 = reinterpret_cast<bf16*>(smem + 65536);    //  8 KB
  bf16* Qb1 = reinterpret_cast<bf16*>(smem + 73728);    //  8 KB
  float (*red)[64] = reinterpret_cast<float (*)[64]>(smem + 65536);  // post-loop alias
  bf16* Pst = reinterpret_cast<bf16*>(smem);            // 32 KB post-loop alias
  const char* Kbase = (const char*)Pk + (size_t)bh*524288 + wave*8192 + lane*16;
  const char* Qbase = (const char*)Pq + (size_t)bh*524288 + (size_t)cs*8192 + wave*2048 + lane*16;
  char* Kd0 = (char*)Kb0 + wave*8192;  char* Kd1 = (char*)Kb1 + wave*8192;
  char* Qd0 = (char*)Qb0 + wave*2048;  char* Qd1 = (char*)Qb1 + wave*2048;

#define STAGE(kb, K_, Q_) { \
    const char* kc = Kbase + (size_t)(kb)*32768; \
    _Pragma("unroll") \
    for (int i_ = 0; i_ < 8; i_++) gload16(kc + i_*1024, (K_) + i_*1024); \
    const char* qc = Qbase + (size_t)(kb)*32768; \
    gload16(qc, (Q_)); gload16(qc + 1024, (Q_) + 1024); }

  f32x4 acc[4][4];
#pragma unroll
  for (int i = 0; i < 4; i++)
#pragma unroll
    for (int j = 0; j < 4; j++) { f32x4 z = {0.f,0.f,0.f,0.f}; acc[i][j] = z; }

  STAGE(0, Kd0, Qd0);
#pragma unroll
  for (int kb = 0; kb < 16; kb++) {
    // stage next chunk into the other buffer (loads stay in flight across barriers)
    if (kb < 15) {
      if (kb & 1) { STAGE(kb+1, Kd0, Qd0); } else { STAGE(kb+1, Kd1, Qd1); }
      asm volatile("s_waitcnt vmcnt(10)" ::: "memory");   // prev chunk complete
    } else {
      asm volatile("s_waitcnt vmcnt(0)" ::: "memory");
    }
    __builtin_amdgcn_s_barrier();
    __builtin_amdgcn_sched_barrier(0);
    const bf16* Kc = (kb & 1) ? Kb1 : Kb0;
    const bf16* Qc = (kb & 1) ? Qb1 : Qb0;
#pragma unroll
    for (int ks = 0; ks < 2; ks++) {
      int colx = (ks*32 + lg*8) ^ ((lr & 7) << 3);
      bf16x8 a[4];
#pragma unroll
      for (int mi = 0; mi < 4; mi++)
        a[mi] = *reinterpret_cast<const bf16x8*>(Qc + (mi*16 + lr)*64 + colx);
#pragma unroll
      for (int ni = 0; ni < 4; ni++) {
        bf16x8 bv2 = *reinterpret_cast<const bf16x8*>(Kc + (wave*64 + ni*16 + lr)*64 + colx);
#pragma unroll
        for (int mi = 0; mi < 4; mi++)
          acc[mi][ni] = __builtin_amdgcn_mfma_f32_16x16x32_bf16(a[mi], bv2, acc[mi][ni], 0, 0, 0);
      }
    }
    __builtin_amdgcn_s_barrier();        // all reads of this buffer done
    __builtin_amdgcn_sched_barrier(0);
  }
#undef STAGE
  // softmax over d (wave holds 64 d; combine 4 waves via red[4][64])
  const float scale = 0.03125f;
  float sums[4][4];
#pragma unroll
  for (int mi = 0; mi < 4; mi++)
#pragma unroll
    for (int r = 0; r < 4; r++) {
      float mx = fmaxf(fmaxf(acc[mi][0][r], acc[mi][1][r]), fmaxf(acc[mi][2][r], acc[mi][3][r]));
#pragma unroll
      for (int off = 1; off < 16; off <<= 1) mx = fmaxf(mx, __shfl_xor(mx, off, 64));
      red[wave][mi*16 + lg*4 + r] = mx;
    }
  __syncthreads();
#pragma unroll
  for (int mi = 0; mi < 4; mi++)
#pragma unroll
    for (int r = 0; r < 4; r++) {
      int clr = mi*16 + lg*4 + r;
      float mx = fmaxf(fmaxf(red[0][clr], red[1][clr]), fmaxf(red[2][clr], red[3][clr]));
      float s = 0.f;
#pragma unroll
      for (int ni = 0; ni < 4; ni++) {
        float p = __expf(scale*(acc[mi][ni][r] - mx));
        acc[mi][ni][r] = p; s += p;
      }
#pragma unroll
      for (int off = 1; off < 16; off <<= 1) s += __shfl_xor(s, off, 64);
      sums[mi][r] = s;
    }
  __syncthreads();
#pragma unroll
  for (int mi = 0; mi < 4; mi++)
#pragma unroll
    for (int r = 0; r < 4; r++) red[wave][mi*16 + lg*4 + r] = sums[mi][r];
  __syncthreads();
  // normalize + stage P strip into LDS (alias over K buffers) in swizzled layout
#pragma unroll
  for (int mi = 0; mi < 4; mi++)
#pragma unroll
    for (int r = 0; r < 4; r++) {
      int clr = mi*16 + lg*4 + r;
      float iv = 1.f/(red[0][clr] + red[1][clr] + red[2][clr] + red[3][clr]);
#pragma unroll
      for (int ni = 0; ni < 4; ni++) {
        int dl = ni*16 + lr;                     // d within wave's 64-chunk
        Pst[wave*4096 + clr*64 + (dl ^ ((clr & 7) << 3))] = (bf16)(acc[mi][ni][r]*iv);
      }
    }
  __syncthreads();
  // coalesced copy-out: 32 KB total; Pattn chunk kb gets rows cs*64..+64
  const uint4* ls = reinterpret_cast<const uint4*>(Pst);
#pragma unroll
  for (int i = 0; i < 8; i++) {
    int f = i*256 + t;              // 2048 uint4
    int kb = f >> 9, rem = f & 511;
    char* dst = (char*)Pattn + ((size_t)(bh*4 + kb)*256 + cs*64)*128 + (size_t)rem*16;
    *reinterpret_cast<uint4*>(dst) = ls[f];
  }
}

// ---------------- Kernel C: O = Pattn * V (K=256), fused deconv + bias + residual
__global__ __launch_bounds__(256, 4) void pv_deconv(const bf16* __restrict__ Pattn,
    const bf16* __restrict__ Vt, const float* __restrict__ qin,
    const float* __restrict__ wo, const float* __restrict__ bo,
    const float* __restrict__ gamma, float* __restrict__ outp) {
  int raw = blockIdx.x;
  int idx = raw >> 3;
  int pair = (raw & 7)*32 + (idx >> 2);   // (mb,bh); 4 tb-blocks share V chunk + XCD
  int tb = idx & 3;
  int mb = pair & 3, bh = pair >> 2;
  int h = bh & 7, b = bh >> 3;
  int t = threadIdx.x, wave = t >> 6, lane = t & 63, lg = lane >> 4, lr = lane & 15;
  __shared__ __attribute__((aligned(16))) char smem[40960];
  bf16* Pl   = reinterpret_cast<bf16*>(smem);            // 8192 B
  bf16* Vl   = reinterpret_cast<bf16*>(smem + 8192);     // 32768 B
  bf16* OlT  = reinterpret_cast<bf16*>(smem);            // 256*66*2 = 33792 B (post-loop)
  float* wo_s = reinterpret_cast<float*>(smem + 36864);  // 1024 B (post-loop)
  float* bo_s = reinterpret_cast<float*>(smem + 37888);  // 32 B
  const char* Pbase = (const char*)Pattn + ((size_t)bh*4*256 + tb*64)*128;
  const char* Vbase = (const char*)Vt + ((size_t)bh*4*1024 + mb*256)*128;
  f32x4 acc[4][4];
#pragma unroll
  for (int i = 0; i < 4; i++)
#pragma unroll
    for (int j = 0; j < 4; j++) { f32x4 z = {0.f,0.f,0.f,0.f}; acc[i][j] = z; }
  for (int kb = 0; kb < 4; kb++) {
    __syncthreads();
    {
      const char* pc = Pbase + (size_t)kb*32768 + wave*2048 + lane*16;
      char* pl = (char*)Pl + wave*2048;
#pragma unroll
      for (int i = 0; i < 2; i++) gload16(pc + i*1024, pl + i*1024);
      const char* vc = Vbase + (size_t)kb*131072 + wave*8192 + lane*16;
      char* vl = (char*)Vl + wave*8192;
#pragma unroll
      for (int i = 0; i < 8; i++) gload16(vc + i*1024, vl + i*1024);
    }
    __syncthreads();
#pragma unroll
    for (int ks = 0; ks < 2; ks++) {
      int colx = (ks*32 + lg*8) ^ ((lr & 7) << 3);
      bf16x8 a[4];
#pragma unroll
      for (int mi = 0; mi < 4; mi++)
        a[mi] = *reinterpret_cast<const bf16x8*>(Pl + (mi*16 + lr)*64 + colx);
#pragma unroll
      for (int ni = 0; ni < 4; ni++) {
        bf16x8 bv2 = *reinterpret_cast<const bf16x8*>(Vl + (wave*64 + ni*16 + lr)*64 + colx);
#pragma unroll
        for (int mi = 0; mi < 4; mi++)
          acc[mi][ni] = __builtin_amdgcn_mfma_f32_16x16x32_bf16(a[mi], bv2, acc[mi][ni], 0, 0, 0);
      }
    }
  }
  __syncthreads();   // all MFMA LDS reads done before OlT/wo_s overwrite
#pragma unroll
  for (int mi = 0; mi < 4; mi++)
#pragma unroll
    for (int ni = 0; ni < 4; ni++) {
      int l = wave*64 + ni*16 + lr;
      int cb = mi*16 + lg*4;
      bf16x4 p;
      p[0] = (bf16)acc[mi][ni][0]; p[1] = (bf16)acc[mi][ni][1];
      p[2] = (bf16)acc[mi][ni][2]; p[3] = (bf16)acc[mi][ni][3];
      *reinterpret_cast<bf16x4*>(OlT + l*66 + cb) = p;
    }
  wo_s[t] = wo[((size_t)(h*32 + tb*8 + (t>>5)))*32 + (t & 31)];
  if (t < 8) bo_s[t] = bo[h*32 + tb*8 + t];
  __syncthreads();
  // epilogue: deconv 2x2 stride 2 + bias + residual; fully coalesced float4 I/O
  int xq = t & 15, b5 = (t >> 4) & 1, ct = t >> 5;
  float2 wp[8];
#pragma unroll
  for (int j = 0; j < 8; j++)
    wp[j] = *reinterpret_cast<const float2*>(wo_s + ct*32 + j*4 + (1 - b5)*2);
  float bias = bo_s[ct];
  float gm = gamma[0];
  int co = h*32 + tb*8 + ct;
#pragma unroll
  for (int it = 0; it < 8; it++) {
    int y = it*2 + b5;
    int ll0 = it*32 + xq*2;
    bf16x4 o00 = *reinterpret_cast<const bf16x4*>(OlT + ll0*66 + ct*8);
    bf16x4 o01 = *reinterpret_cast<const bf16x4*>(OlT + ll0*66 + ct*8 + 4);
    bf16x4 o10 = *reinterpret_cast<const bf16x4*>(OlT + (ll0+1)*66 + ct*8);
    bf16x4 o11 = *reinterpret_cast<const bf16x4*>(OlT + (ll0+1)*66 + ct*8 + 4);
    float v0 = bias, v1 = bias, v2 = bias, v3 = bias;
#pragma unroll
    for (int j = 0; j < 4; j++) {
      float f0 = (float)o00[j], f1 = (float)o01[j];
      v0 += f0*wp[j].y;   v1 += f0*wp[j].x;
      v0 += f1*wp[4+j].y; v1 += f1*wp[4+j].x;
      float g0 = (float)o10[j], g1 = (float)o11[j];
      v2 += g0*wp[j].y;   v3 += g0*wp[j].x;
      v2 += g1*wp[4+j].y; v3 += g1*wp[4+j].x;
    }
    size_t oi = (((size_t)b*256 + co)*64 + (mb*16 + y))*64 + xq*4;
    float4 qv = *reinterpret_cast<const float4*>(qin + oi);
    float4 ov;
    ov.x = qv.x + gm*v0; ov.y = qv.y + gm*v1;
    ov.z = qv.z + gm*v2; ov.w = qv.w + gm*v3;
    *reinterpret_cast<float4*>(outp + oi) = ov;
  }
}

extern "C" void kernel_launch(void* const* d_in, const int* in_sizes, int n_in,
                              void* d_out, int out_size, void* d_ws, size_t ws_size,
                              hipStream_t stream) {
  const float* q  = (const float*)d_in[0];
  const float* k  = (const float*)d_in[1];
  const float* v  = (const float*)d_in[2];
  const float* wq = (const float*)d_in[3];
  const float* bq = (const float*)d_in[4];
  const float* wk = (const float*)d_in[5];
  const float* bk = (const float*)d_in[6];
  const float* wv = (const float*)d_in[7];
  const float* bv = (const float*)d_in[8];
  const float* wo = (const float*)d_in[9];
  const float* bo = (const float*)d_in[10];
  const float* gamma = (const float*)d_in[11];
  float* out = (float*)d_out;

  char* ws = (char*)d_ws;
  bf16* Pk    = (bf16*)(ws);              //  33,554,432 B
  bf16* Vt    = (bf16*)(ws + 33554432);   //  33,554,432 B
  bf16* Pattn = (bf16*)(ws + 67108864);   //   8,388,608 B
  bf16* Pq    = (bf16*)(ws + 75497472);   //  33,554,432 B

  proj_kqv<<<dim3(768, 8), 256, 0, stream>>>(k, q, v, wk, bk, wq, bq, wv, bv, Pk, Pq, Vt);
  attn_qk <<<dim3(256), 256, 0, stream>>>(Pq, Pk, Pattn);
  pv_deconv<<<dim3(1024), 256, 0, stream>>>(Pattn, Vt, q, wo, bo, gamma, out);
}

// Round 10
// 81.786 us; speedup vs baseline: 1.1363x; 1.1363x over previous
//
#include <hip/hip_runtime.h>
#include <hip/hip_bf16.h>

typedef __bf16 bf16;
typedef __bf16 bf16x4 __attribute__((ext_vector_type(4)));
typedef __bf16 bf16x8 __attribute__((ext_vector_type(8)));
typedef float f32x4 __attribute__((ext_vector_type(4)));

// async global->LDS, 16B per lane. LDS dest must be wave-uniform (HW adds lane*16).
__device__ __forceinline__ void gload16(const void* g, void* l) {
  __builtin_amdgcn_global_load_lds(
      (const __attribute__((address_space(1))) unsigned int*)g,
      (__attribute__((address_space(3))) unsigned int*)l, 16, 0, 0);
}

// Layouts (bf16, BK=64 chunks, 128B rows, swizzle: elem col ^= (row&7)<<3):
//  Pq/Pk: [bh][kb16][row c(256)][64]   (k-dim = l)  row-XOR uses c&7
//  Vt:    [bh][kb4][row l(1024)][64]   (k-dim = c)  row-XOR uses l&7
//  Pattn: [bh][kb4][row c(256)][64]    (k-dim = d)  row-XOR uses c&7

// ---------------- Kernel A: k/q/v projections in one launch (x<256:k, <512:q, else v)
__global__ __launch_bounds__(256) void proj_kqv(
    const float* __restrict__ kin, const float* __restrict__ qin,
    const float* __restrict__ vin,
    const float* __restrict__ wk, const float* __restrict__ bk,
    const float* __restrict__ wq, const float* __restrict__ bq,
    const float* __restrict__ wv, const float* __restrict__ bv,
    bf16* __restrict__ Pk, bf16* __restrict__ Pq, bf16* __restrict__ Vt) {
  int b = blockIdx.y;
  int x = blockIdx.x;
  int t = threadIdx.x;
  __shared__ float ch[4288];   // k/q-path: 4096 linear; v-path: 32*2*67
  if (x < 512) {
    // ---- k or q projection: LDS-staged channel (coalesced), broadcast reads,
    // 1KB-coalesced swizzled stores. Lane (j,n) = ((t>>3)&7, t&7); wave -> kb.
    int g = x & 255;
    const float* in   = (x < 256) ? kin : qin;
    const float* w    = (x < 256) ? wk : wq;
    const float* bias = (x < 256) ? bk : bq;
    bf16* out         = (x < 256) ? Pk : Pq;
    {
      const float4* src = reinterpret_cast<const float4*>(in + ((size_t)b*256 + g)*4096);
      float4* dst4 = reinterpret_cast<float4*>(ch);
#pragma unroll
      for (int i = 0; i < 4; i++) dst4[t + i*256] = src[t + i*256];
    }
    int wave = t >> 6;
    int j = (t >> 3) & 7, n = t & 7;
    float4 wvv = reinterpret_cast<const float4*>(w)[g*8 + j];
    float bj = bias[g*8 + j];
    __syncthreads();
    int h = g >> 5;
    int c0 = (g & 31)*8;
    int bh = b*8 + h;
#pragma unroll
    for (int p = 0; p < 4; p++) {
      int kb = p*4 + wave;
      int m = kb*2 + (n >> 2);          // spatial out-row of this granule
      int n0 = (n & 3)*8;               // first out-col
      float rr0[16], rr1[16];
      const float4* R0 = reinterpret_cast<const float4*>(ch + (2*m)*64 + 2*n0);
      const float4* R1 = reinterpret_cast<const float4*>(ch + (2*m+1)*64 + 2*n0);
#pragma unroll
      for (int u = 0; u < 4; u++) {
        *reinterpret_cast<float4*>(rr0 + u*4) = R0[u];
        *reinterpret_cast<float4*>(rr1 + u*4) = R1[u];
      }
      bf16x8 o;
#pragma unroll
      for (int u = 0; u < 8; u++)
        o[u] = (bf16)(bj + wvv.x*rr0[2*u] + wvv.y*rr0[2*u+1] + wvv.z*rr1[2*u] + wvv.w*rr1[2*u+1]);
      // granule n of row c0+j, swizzled to col-granule n^j; wave covers 1KB contiguous
      size_t off = (((size_t)bh*16 + kb)*256 + c0 + j)*64 + (size_t)((n ^ j)*8);
      *reinterpret_cast<bf16x8*>(out + off) = o;
    }
  } else {
    // ---- v projection into swizzled chunk-transposed Vt (LDS pad 67: 2-way max)
    int r = x - 512;
    int m = r & 31, h = r >> 5;
    {
      int seg = t >> 2, part = t & 3;
      int gl = seg >> 1, ky = seg & 1;
      const float* src = vin + (((size_t)b*256 + h*32 + gl)*64 + (2*m + ky))*64;
      float* drow = ch + (gl*2 + ky)*67;
#pragma unroll
      for (int i = 0; i < 4; i++) {
        float4 v = reinterpret_cast<const float4*>(src)[part + i*4];
        int x0 = (part + i*4)*4;
        drow[x0]=v.x; drow[x0+1]=v.y; drow[x0+2]=v.z; drow[x0+3]=v.w;
      }
    }
    int cgrp = t & 31, lgr = t >> 5;
    int c0 = cgrp*8;
    float4 wv8[8]; float bb8[8];
#pragma unroll
    for (int u = 0; u < 8; u++) {
      wv8[u] = reinterpret_cast<const float4*>(wv)[h*256 + c0 + u];
      bb8[u] = bv[h*256 + c0 + u];
    }
    __syncthreads();
    const float* r0 = ch + (cgrp*2 + 0)*67;
    const float* r1 = ch + (cgrp*2 + 1)*67;
    int bh = b*8 + h;
    bf16* base = Vt + ((size_t)bh*4 + (c0 >> 6))*1024*64;
    int colx = (c0 & 63) ^ (lgr << 3);
#pragma unroll
    for (int p = 0; p < 4; p++) {
      int n = p*8 + lgr;
      int l = m*32 + n;
      float c00 = r0[2*n], c01 = r0[2*n+1], c10 = r1[2*n], c11 = r1[2*n+1];
      bf16x8 o;
#pragma unroll
      for (int u = 0; u < 8; u++)
        o[u] = (bf16)(bb8[u] + wv8[u].x*c00 + wv8[u].y*c01 + wv8[u].z*c10 + wv8[u].w*c11);
      *reinterpret_cast<bf16x8*>(base + (size_t)l*64 + colx) = o;
    }
  }
}

// ---------------- Kernel B: S = Q K^T + softmax -> Pattn.  BM=64, 256 blocks,
// 4 waves; wave tile 64c x 64d (4x4 frags, 32 MFMA/chunk).  T3/T4 2-phase
// counted-vmcnt pipeline: K+Q double-buffered LDS via gload16, vmcnt(10) never 0.
__global__ __launch_bounds__(256, 2) void attn_qk(
    const bf16* __restrict__ Pq, const bf16* __restrict__ Pk,
    bf16* __restrict__ Pattn) {
  int raw = blockIdx.x;
  int idx = raw >> 3;
  int bh = (raw & 7)*8 + (idx >> 2);   // 4 c-strips of one bh share an XCD
  int cs = idx & 3;
  int t = threadIdx.x, wave = t >> 6, lane = t & 63, lg = lane >> 4, lr = lane & 15;
  __shared__ __attribute__((aligned(16))) char smem[81920];
  bf16* Kb0 = reinterpret_cast<bf16*>(smem);            // 32 KB
  bf16* Kb1 = reinterpret_cast<bf16*>(smem + 32768);    // 32 KB
  bf16* Qb0 = reinterpret_cast<bf16*>(smem + 65536);    //  8 KB
  bf16* Qb1 = reinterpret_cast<bf16*>(smem + 73728);    //  8 KB
  float (*red)[64] = reinterpret_cast<float (*)[64]>(smem + 65536);  // post-loop alias
  bf16* Pst = reinterpret_cast<bf16*>(smem);            // 32 KB post-loop alias
  const char* Kbase = (const char*)Pk + (size_t)bh*524288 + wave*8192 + lane*16;
  const char* Qbase = (const char*)Pq + (size_t)bh*524288 + (size_t)cs*8192 + wave*2048 + lane*16;
  char* Kd0 = (char*)Kb0 + wave*8192;  char* Kd1 = (char*)Kb1 + wave*8192;
  char* Qd0 = (char*)Qb0 + wave*2048;  char* Qd1 = (char*)Qb1 + wave*2048;

#define STAGE(kb, K_, Q_) { \
    const char* kc = Kbase + (size_t)(kb)*32768; \
    _Pragma("unroll") \
    for (int i_ = 0; i_ < 8; i_++) gload16(kc + i_*1024, (K_) + i_*1024); \
    const char* qc = Qbase + (size_t)(kb)*32768; \
    gload16(qc, (Q_)); gload16(qc + 1024, (Q_) + 1024); }

  f32x4 acc[4][4];
#pragma unroll
  for (int i = 0; i < 4; i++)
#pragma unroll
    for (int j = 0; j < 4; j++) { f32x4 z = {0.f,0.f,0.f,0.f}; acc[i][j] = z; }

  STAGE(0, Kd0, Qd0);
#pragma unroll
  for (int kb = 0; kb < 16; kb++) {
    // stage next chunk into the other buffer (loads stay in flight across barriers)
    if (kb < 15) {
      if (kb & 1) { STAGE(kb+1, Kd0, Qd0); } else { STAGE(kb+1, Kd1, Qd1); }
      asm volatile("s_waitcnt vmcnt(10)" ::: "memory");   // prev chunk complete
    } else {
      asm volatile("s_waitcnt vmcnt(0)" ::: "memory");
    }
    __builtin_amdgcn_s_barrier();
    __builtin_amdgcn_sched_barrier(0);
    const bf16* Kc = (kb & 1) ? Kb1 : Kb0;
    const bf16* Qc = (kb & 1) ? Qb1 : Qb0;
#pragma unroll
    for (int ks = 0; ks < 2; ks++) {
      int colx = (ks*32 + lg*8) ^ ((lr & 7) << 3);
      bf16x8 a[4];
#pragma unroll
      for (int mi = 0; mi < 4; mi++)
        a[mi] = *reinterpret_cast<const bf16x8*>(Qc + (mi*16 + lr)*64 + colx);
#pragma unroll
      for (int ni = 0; ni < 4; ni++) {
        bf16x8 bv2 = *reinterpret_cast<const bf16x8*>(Kc + (wave*64 + ni*16 + lr)*64 + colx);
#pragma unroll
        for (int mi = 0; mi < 4; mi++)
          acc[mi][ni] = __builtin_amdgcn_mfma_f32_16x16x32_bf16(a[mi], bv2, acc[mi][ni], 0, 0, 0);
      }
    }
    __builtin_amdgcn_s_barrier();        // all reads of this buffer done
    __builtin_amdgcn_sched_barrier(0);
  }
#undef STAGE
  // softmax over d (wave holds 64 d; combine 4 waves via red[4][64])
  const float scale = 0.03125f;
  float sums[4][4];
#pragma unroll
  for (int mi = 0; mi < 4; mi++)
#pragma unroll
    for (int r = 0; r < 4; r++) {
      float mx = fmaxf(fmaxf(acc[mi][0][r], acc[mi][1][r]), fmaxf(acc[mi][2][r], acc[mi][3][r]));
#pragma unroll
      for (int off = 1; off < 16; off <<= 1) mx = fmaxf(mx, __shfl_xor(mx, off, 64));
      red[wave][mi*16 + lg*4 + r] = mx;
    }
  __syncthreads();
#pragma unroll
  for (int mi = 0; mi < 4; mi++)
#pragma unroll
    for (int r = 0; r < 4; r++) {
      int clr = mi*16 + lg*4 + r;
      float mx = fmaxf(fmaxf(red[0][clr], red[1][clr]), fmaxf(red[2][clr], red[3][clr]));
      float s = 0.f;
#pragma unroll
      for (int ni = 0; ni < 4; ni++) {
        float p = __expf(scale*(acc[mi][ni][r] - mx));
        acc[mi][ni][r] = p; s += p;
      }
#pragma unroll
      for (int off = 1; off < 16; off <<= 1) s += __shfl_xor(s, off, 64);
      sums[mi][r] = s;
    }
  __syncthreads();
#pragma unroll
  for (int mi = 0; mi < 4; mi++)
#pragma unroll
    for (int r = 0; r < 4; r++) red[wave][mi*16 + lg*4 + r] = sums[mi][r];
  __syncthreads();
  // normalize + stage P strip into LDS (alias over K buffers) in swizzled layout
#pragma unroll
  for (int mi = 0; mi < 4; mi++)
#pragma unroll
    for (int r = 0; r < 4; r++) {
      int clr = mi*16 + lg*4 + r;
      float iv = 1.f/(red[0][clr] + red[1][clr] + red[2][clr] + red[3][clr]);
#pragma unroll
      for (int ni = 0; ni < 4; ni++) {
        int dl = ni*16 + lr;                     // d within wave's 64-chunk
        Pst[wave*4096 + clr*64 + (dl ^ ((clr & 7) << 3))] = (bf16)(acc[mi][ni][r]*iv);
      }
    }
  __syncthreads();
  // coalesced copy-out: 32 KB total; Pattn chunk kb gets rows cs*64..+64
  const uint4* ls = reinterpret_cast<const uint4*>(Pst);
#pragma unroll
  for (int i = 0; i < 8; i++) {
    int f = i*256 + t;              // 2048 uint4
    int kb = f >> 9, rem = f & 511;
    char* dst = (char*)Pattn + ((size_t)(bh*4 + kb)*256 + cs*64)*128 + (size_t)rem*16;
    *reinterpret_cast<uint4*>(dst) = ls[f];
  }
}

// ---------------- Kernel C: O = Pattn * V (K=256), fused deconv + bias + residual
__global__ __launch_bounds__(256, 4) void pv_deconv(const bf16* __restrict__ Pattn,
    const bf16* __restrict__ Vt, const float* __restrict__ qin,
    const float* __restrict__ wo, const float* __restrict__ bo,
    const float* __restrict__ gamma, float* __restrict__ outp) {
  int raw = blockIdx.x;
  int idx = raw >> 3;
  int pair = (raw & 7)*32 + (idx >> 2);   // (mb,bh); 4 tb-blocks share V chunk + XCD
  int tb = idx & 3;
  int mb = pair & 3, bh = pair >> 2;
  int h = bh & 7, b = bh >> 3;
  int t = threadIdx.x, wave = t >> 6, lane = t & 63, lg = lane >> 4, lr = lane & 15;
  __shared__ __attribute__((aligned(16))) char smem[40960];
  bf16* Pl   = reinterpret_cast<bf16*>(smem);            // 8192 B
  bf16* Vl   = reinterpret_cast<bf16*>(smem + 8192);     // 32768 B
  bf16* OlT  = reinterpret_cast<bf16*>(smem);            // 256*66*2 = 33792 B (post-loop)
  float* wo_s = reinterpret_cast<float*>(smem + 36864);  // 1024 B (post-loop)
  float* bo_s = reinterpret_cast<float*>(smem + 37888);  // 32 B
  const char* Pbase = (const char*)Pattn + ((size_t)bh*4*256 + tb*64)*128;
  const char* Vbase = (const char*)Vt + ((size_t)bh*4*1024 + mb*256)*128;
  f32x4 acc[4][4];
#pragma unroll
  for (int i = 0; i < 4; i++)
#pragma unroll
    for (int j = 0; j < 4; j++) { f32x4 z = {0.f,0.f,0.f,0.f}; acc[i][j] = z; }
  for (int kb = 0; kb < 4; kb++) {
    __syncthreads();
    {
      const char* pc = Pbase + (size_t)kb*32768 + wave*2048 + lane*16;
      char* pl = (char*)Pl + wave*2048;
#pragma unroll
      for (int i = 0; i < 2; i++) gload16(pc + i*1024, pl + i*1024);
      const char* vc = Vbase + (size_t)kb*131072 + wave*8192 + lane*16;
      char* vl = (char*)Vl + wave*8192;
#pragma unroll
      for (int i = 0; i < 8; i++) gload16(vc + i*1024, vl + i*1024);
    }
    __syncthreads();
#pragma unroll
    for (int ks = 0; ks < 2; ks++) {
      int colx = (ks*32 + lg*8) ^ ((lr & 7) << 3);
      bf16x8 a[4];
#pragma unroll
      for (int mi = 0; mi < 4; mi++)
        a[mi] = *reinterpret_cast<const bf16x8*>(Pl + (mi*16 + lr)*64 + colx);
#pragma unroll
      for (int ni = 0; ni < 4; ni++) {
        bf16x8 bv2 = *reinterpret_cast<const bf16x8*>(Vl + (wave*64 + ni*16 + lr)*64 + colx);
#pragma unroll
        for (int mi = 0; mi < 4; mi++)
          acc[mi][ni] = __builtin_amdgcn_mfma_f32_16x16x32_bf16(a[mi], bv2, acc[mi][ni], 0, 0, 0);
      }
    }
  }
  __syncthreads();   // all MFMA LDS reads done before OlT/wo_s overwrite
#pragma unroll
  for (int mi = 0; mi < 4; mi++)
#pragma unroll
    for (int ni = 0; ni < 4; ni++) {
      int l = wave*64 + ni*16 + lr;
      int cb = mi*16 + lg*4;
      bf16x4 p;
      p[0] = (bf16)acc[mi][ni][0]; p[1] = (bf16)acc[mi][ni][1];
      p[2] = (bf16)acc[mi][ni][2]; p[3] = (bf16)acc[mi][ni][3];
      *reinterpret_cast<bf16x4*>(OlT + l*66 + cb) = p;
    }
  wo_s[t] = wo[((size_t)(h*32 + tb*8 + (t>>5)))*32 + (t & 31)];
  if (t < 8) bo_s[t] = bo[h*32 + tb*8 + t];
  __syncthreads();
  // epilogue: deconv 2x2 stride 2 + bias + residual; fully coalesced float4 I/O
  int xq = t & 15, b5 = (t >> 4) & 1, ct = t >> 5;
  float2 wp[8];
#pragma unroll
  for (int j = 0; j < 8; j++)
    wp[j] = *reinterpret_cast<const float2*>(wo_s + ct*32 + j*4 + (1 - b5)*2);
  float bias = bo_s[ct];
  float gm = gamma[0];
  int co = h*32 + tb*8 + ct;
#pragma unroll
  for (int it = 0; it < 8; it++) {
    int y = it*2 + b5;
    int ll0 = it*32 + xq*2;
    bf16x4 o00 = *reinterpret_cast<const bf16x4*>(OlT + ll0*66 + ct*8);
    bf16x4 o01 = *reinterpret_cast<const bf16x4*>(OlT + ll0*66 + ct*8 + 4);
    bf16x4 o10 = *reinterpret_cast<const bf16x4*>(OlT + (ll0+1)*66 + ct*8);
    bf16x4 o11 = *reinterpret_cast<const bf16x4*>(OlT + (ll0+1)*66 + ct*8 + 4);
    float v0 = bias, v1 = bias, v2 = bias, v3 = bias;
#pragma unroll
    for (int j = 0; j < 4; j++) {
      float f0 = (float)o00[j], f1 = (float)o01[j];
      v0 += f0*wp[j].y;   v1 += f0*wp[j].x;
      v0 += f1*wp[4+j].y; v1 += f1*wp[4+j].x;
      float g0 = (float)o10[j], g1 = (float)o11[j];
      v2 += g0*wp[j].y;   v3 += g0*wp[j].x;
      v2 += g1*wp[4+j].y; v3 += g1*wp[4+j].x;
    }
    size_t oi = (((size_t)b*256 + co)*64 + (mb*16 + y))*64 + xq*4;
    float4 qv = *reinterpret_cast<const float4*>(qin + oi);
    float4 ov;
    ov.x = qv.x + gm*v0; ov.y = qv.y + gm*v1;
    ov.z = qv.z + gm*v2; ov.w = qv.w + gm*v3;
    *reinterpret_cast<float4*>(outp + oi) = ov;
  }
}

extern "C" void kernel_launch(void* const* d_in, const int* in_sizes, int n_in,
                              void* d_out, int out_size, void* d_ws, size_t ws_size,
                              hipStream_t stream) {
  const float* q  = (const float*)d_in[0];
  const float* k  = (const float*)d_in[1];
  const float* v  = (const float*)d_in[2];
  const float* wq = (const float*)d_in[3];
  const float* bq = (const float*)d_in[4];
  const float* wk = (const float*)d_in[5];
  const float* bk = (const float*)d_in[6];
  const float* wv = (const float*)d_in[7];
  const float* bv = (const float*)d_in[8];
  const float* wo = (const float*)d_in[9];
  const float* bo = (const float*)d_in[10];
  const float* gamma = (const float*)d_in[11];
  float* out = (float*)d_out;

  char* ws = (char*)d_ws;
  bf16* Pk    = (bf16*)(ws);              //  33,554,432 B
  bf16* Vt    = (bf16*)(ws + 33554432);   //  33,554,432 B
  bf16* Pattn = (bf16*)(ws + 67108864);   //   8,388,608 B
  bf16* Pq    = (bf16*)(ws + 75497472);   //  33,554,432 B

  proj_kqv<<<dim3(768, 8), 256, 0, stream>>>(k, q, v, wk, bk, wq, bq, wv, bv, Pk, Pq, Vt);
  attn_qk <<<dim3(256), 256, 0, stream>>>(Pq, Pk, Pattn);
  pv_deconv<<<dim3(1024), 256, 0, stream>>>(Pattn, Vt, q, wo, bo, gamma, out);
}